// Round 3
// baseline (504.814 us; speedup 1.0000x reference)
//
#include <hip/hip_runtime.h>

typedef __attribute__((ext_vector_type(8))) short short8;
typedef __attribute__((ext_vector_type(4))) float f32x4;

#define LOG2E 1.44269504088896340736f

__device__ __forceinline__ unsigned pkcvt(float lo, float hi) {   // 1-instr bf16 pack
    unsigned r;
    asm("v_cvt_pk_bf16_f32 %0, %1, %2" : "=v"(r) : "v"(lo), "v"(hi));
    return r;
}
__device__ __forceinline__ float sigm(float x) {       // sigmoid via exp2+rcp
    return __builtin_amdgcn_rcpf(1.0f + __builtin_amdgcn_exp2f(-LOG2E * x));
}

// B=2048, T=512, I=64, H=32.
// R3: transpose the recurrent MFMA so the h-exchange needs NO LDS crossbar.
//   A = permuted W_hh (8 tiles, gr(t,r) = (t>>1)*32 + 8*(r>>2) + (t&1)*4 + (r&3))
//   B = h, col m carries batch row (m>>3)  -> TWO rows per wave.
// Lane (m,q) receives gates for cols 8q + (t&1)*4 + j of its row -- exactly the
// col-block its next B-frag needs. Cols split 2/lane by g=m&3; h-exchange is
// 1 cvt_pk + shfl_xor(1,2) (DPP quad_perm) + 6 cndmask. Step-loop LDS = 2
// prefetchable xg reads only. 1024 waves = 256 blocks = 1 block/CU, 1 wave/SIMD.
__global__ __launch_bounds__(256, 1) void lstm_fused(
    const float* __restrict__ x,    // [2048,512,64]
    const float* __restrict__ Wih,  // [128,64]
    const float* __restrict__ Whh,  // [128,32]
    const float* __restrict__ bih,  // [128]
    const float* __restrict__ bhh,  // [128]
    const float* __restrict__ Wfc,  // [1,32]
    const float* __restrict__ bfc,  // [1]
    float* __restrict__ out)        // [2048,1]
{
    __shared__ unsigned short Wlds[128 * 80];   // W_ih bf16, stride 80 (20480 B)
    // per-wave xg: [rm][tt][q-block 36][col 4 + gate]; rm-stride 2384, tt-stride 148
    __shared__ float xg_sh[4 * 4768];           // 76288 B  (total LDS 96768 B)

    const int tid  = threadIdx.x;
    const int lane = tid & 63;
    const int wv   = tid >> 6;
    const int b0   = blockIdx.x * 8 + wv * 2;   // two batch rows per wave
    const int m    = lane & 15;
    const int q    = lane >> 4;
    const int g    = m & 3;        // col-pair group: lane owns cols 8q+2g, 8q+2g+1
    const int rm   = (m >> 3) & 1; // lane's batch row (b0+rm)

    // ---- cooperative W_ih -> LDS (bf16, padded rows) ----
    {
        const float4* w4 = (const float4*)Wih;
        unsigned* wl = (unsigned*)Wlds;
        #pragma unroll
        for (int i = 0; i < 8; i++) {
            int fi = tid * 8 + i;            // float4 index, 2048 total
            int gg = fi >> 4;                // gate row
            int k  = (fi & 15) << 2;         // col (float units)
            float4 v = w4[fi];
            wl[gg * 40 + (k >> 1) + 0] = pkcvt(v.x, v.y);
            wl[gg * 40 + (k >> 1) + 1] = pkcvt(v.z, v.w);
        }
    }

    // ---- permuted W_hh A-frags: tile t, lane row m = Whh[gr(t,m)], k=8q..8q+7 ----
    short8 Wr[8];
    #pragma unroll
    for (int t = 0; t < 8; t++) {
        const int gr = (t >> 1) * 32 + 8 * (m >> 2) + (t & 1) * 4 + (m & 3);
        const float4* wr = (const float4*)(Whh + (size_t)gr * 32 + q * 8);
        float4 va = wr[0], vb = wr[1];
        union { short8 v; unsigned u[4]; } B;
        B.u[0] = pkcvt(va.x, va.y); B.u[1] = pkcvt(va.z, va.w);
        B.u[2] = pkcvt(vb.x, vb.y); B.u[3] = pkcvt(vb.z, vb.w);
        Wr[t] = B.v;
    }

    // ---- per-lane scatter bias for xg phase: biasv[n] = bih[16n+m]+bhh[16n+m] ----
    float biasv[8];
    #pragma unroll
    for (int n = 0; n < 8; n++) biasv[n] = bih[16 * n + m] + bhh[16 * n + m];

    __syncthreads();  // Wlds ready

    const float* xrow0 = x + ((size_t)b0 * 512 + m) * 64;   // row b0,  timestep row m
    const float* xrow1 = xrow0 + 512 * 64;                  // row b0+1
    float* xgw = xg_sh + wv * 4768;

    float c0 = 0.0f, c1 = 0.0f, h0 = 0.0f, h1 = 0.0f;
    const f32x4 z4 = {0.f, 0.f, 0.f, 0.f};

    // prefetch chunk 0, both rows
    float4 p0, p1, p2, p3, q0, q1, q2, q3;
    {
        const float4* r0 = (const float4*)xrow0;
        const float4* r1 = (const float4*)xrow1;
        p0 = r0[q * 2];     p1 = r0[q * 2 + 1];
        p2 = r0[8 + q * 2]; p3 = r0[8 + q * 2 + 1];
        q0 = r1[q * 2];     q1 = r1[q * 2 + 1];
        q2 = r1[8 + q * 2]; q3 = r1[8 + q * 2 + 1];
    }

    const float* xb = xgw + rm * 2384 + q * 36 + g * 8;   // step-read base (+tt*148)
    const bool tsel = (g & 2) != 0;
    const bool jsel = (g & 1) != 0;

    for (int ch = 0; ch < 32; ++ch) {
        // ---- pack A-frags for xg (row0: A0/A1, row1: C0/C1) ----
        union { short8 v; unsigned u[4]; } A0, A1, C0, C1;
        A0.u[0] = pkcvt(p0.x, p0.y); A0.u[1] = pkcvt(p0.z, p0.w);
        A0.u[2] = pkcvt(p1.x, p1.y); A0.u[3] = pkcvt(p1.z, p1.w);
        A1.u[0] = pkcvt(p2.x, p2.y); A1.u[1] = pkcvt(p2.z, p2.w);
        A1.u[2] = pkcvt(p3.x, p3.y); A1.u[3] = pkcvt(p3.z, p3.w);
        C0.u[0] = pkcvt(q0.x, q0.y); C0.u[1] = pkcvt(q0.z, q0.w);
        C0.u[2] = pkcvt(q1.x, q1.y); C0.u[3] = pkcvt(q1.z, q1.w);
        C1.u[0] = pkcvt(q2.x, q2.y); C1.u[1] = pkcvt(q2.z, q2.w);
        C1.u[2] = pkcvt(q3.x, q3.y); C1.u[3] = pkcvt(q3.z, q3.w);

        // ---- prefetch next chunk ----
        {
            const int chn = (ch < 31) ? ch + 1 : 31;
            const float4* n0 = (const float4*)(xrow0 + (size_t)chn * 1024);
            const float4* n1 = (const float4*)(xrow1 + (size_t)chn * 1024);
            p0 = n0[q * 2];     p1 = n0[q * 2 + 1];
            p2 = n0[8 + q * 2]; p3 = n0[8 + q * 2 + 1];
            q0 = n1[q * 2];     q1 = n1[q * 2 + 1];
            q2 = n1[8 + q * 2]; q3 = n1[8 + q * 2 + 1];
        }

        // ---- xg for both rows: 32 MFMAs; scatter [rm][tt][col][gate] ----
        #pragma unroll
        for (int n = 0; n < 8; n++) {
            const short8 B0 = *(const short8*)&Wlds[(16 * n + m) * 80 + q * 8];
            const short8 B1 = *(const short8*)&Wlds[(16 * n + m) * 80 + 32 + q * 8];
            f32x4 ar0 = z4, ar1 = z4;
            ar0 = __builtin_amdgcn_mfma_f32_16x16x32_bf16(A0.v, B0, ar0, 0, 0, 0);
            ar0 = __builtin_amdgcn_mfma_f32_16x16x32_bf16(A1.v, B1, ar0, 0, 0, 0);
            ar1 = __builtin_amdgcn_mfma_f32_16x16x32_bf16(C0.v, B0, ar1, 0, 0, 0);
            ar1 = __builtin_amdgcn_mfma_f32_16x16x32_bf16(C1.v, B1, ar1, 0, 0, 0);
            // D: lane holds xg[tt=4q+r][gate 16n+m]; col=(n&1)*16+m, type=n>>1
            const int so = ((n & 1) * 2 + (m >> 3)) * 36 + (m & 7) * 4 + (n >> 1);
            #pragma unroll
            for (int r = 0; r < 4; r++) {
                xgw[(4 * q + r) * 148 + so]        = ar0[r] + biasv[n];
                xgw[2384 + (4 * q + r) * 148 + so] = ar1[r] + biasv[n];
            }
        }

        // ---- 16 recurrent timesteps (no LDS on the h chain) ----
        #pragma unroll
        for (int tt = 0; tt < 16; ++tt) {
            // B-frag: h[8q..8q+7] of this lane's row, via DPP-only exchange
            const int own = (int)pkcvt(h0, h1);            // pair g
            const int x1  = __shfl_xor(own, 1);            // pair g^1 (quad_perm)
            const int plo = jsel ? x1 : own;               // pair 2*(g>>1)
            const int phi = jsel ? own : x1;               // pair 2*(g>>1)+1
            const int qlo = __shfl_xor(plo, 2);            // pairs of g^2 group
            const int qhi = __shfl_xor(phi, 2);
            union { short8 v; int u[4]; } H;
            H.u[0] = tsel ? qlo : plo;
            H.u[1] = tsel ? qhi : phi;
            H.u[2] = tsel ? plo : qlo;
            H.u[3] = tsel ? phi : qhi;

            const f32x4 a0 = __builtin_amdgcn_mfma_f32_16x16x32_bf16(Wr[0], H.v, z4, 0, 0, 0);
            const f32x4 a1 = __builtin_amdgcn_mfma_f32_16x16x32_bf16(Wr[1], H.v, z4, 0, 0, 0);
            const f32x4 a2 = __builtin_amdgcn_mfma_f32_16x16x32_bf16(Wr[2], H.v, z4, 0, 0, 0);
            const f32x4 a3 = __builtin_amdgcn_mfma_f32_16x16x32_bf16(Wr[3], H.v, z4, 0, 0, 0);
            const f32x4 a4 = __builtin_amdgcn_mfma_f32_16x16x32_bf16(Wr[4], H.v, z4, 0, 0, 0);
            const f32x4 a5 = __builtin_amdgcn_mfma_f32_16x16x32_bf16(Wr[5], H.v, z4, 0, 0, 0);
            const f32x4 a6 = __builtin_amdgcn_mfma_f32_16x16x32_bf16(Wr[6], H.v, z4, 0, 0, 0);
            const f32x4 a7 = __builtin_amdgcn_mfma_f32_16x16x32_bf16(Wr[7], H.v, z4, 0, 0, 0);

            // xg reads (prefetchable, off-chain): cols 2g, 2g+1 -> [i,f,g,o] each
            const f32x4 xgA = *(const f32x4*)(xb + tt * 148);
            const f32x4 xgB = *(const f32x4*)(xb + tt * 148 + 4);

            // extract lane's 8 gate values: tile 2G + (g>>1), regs 2*(g&1), +1
            float vi0, vi1, vf0, vf1, vg0, vg1, vo0, vo1;
            {
                const float e0 = tsel ? a1[0] : a0[0], e1 = tsel ? a1[1] : a0[1];
                const float e2 = tsel ? a1[2] : a0[2], e3 = tsel ? a1[3] : a0[3];
                vi0 = jsel ? e2 : e0; vi1 = jsel ? e3 : e1;
            }
            {
                const float e0 = tsel ? a3[0] : a2[0], e1 = tsel ? a3[1] : a2[1];
                const float e2 = tsel ? a3[2] : a2[2], e3 = tsel ? a3[3] : a2[3];
                vf0 = jsel ? e2 : e0; vf1 = jsel ? e3 : e1;
            }
            {
                const float e0 = tsel ? a5[0] : a4[0], e1 = tsel ? a5[1] : a4[1];
                const float e2 = tsel ? a5[2] : a4[2], e3 = tsel ? a5[3] : a4[3];
                vg0 = jsel ? e2 : e0; vg1 = jsel ? e3 : e1;
            }
            {
                const float e0 = tsel ? a7[0] : a6[0], e1 = tsel ? a7[1] : a6[1];
                const float e2 = tsel ? a7[2] : a6[2], e3 = tsel ? a7[3] : a6[3];
                vo0 = jsel ? e2 : e0; vo1 = jsel ? e3 : e1;
            }

            // col 0 (8q+2g)
            const float gi0 = xgA[0] + vi0, gf0 = xgA[1] + vf0;
            const float gg0 = xgA[2] + vg0, go0 = xgA[3] + vo0;
            const float iv0 = sigm(gi0), fv0 = sigm(gf0), ov0 = sigm(go0);
            const float gv0 = fmaf(2.0f, sigm(2.0f * gg0), -1.0f);
            c0 = fmaf(fv0, c0, iv0 * gv0);
            h0 = ov0 * fmaf(2.0f, sigm(2.0f * c0), -1.0f);
            // col 1 (8q+2g+1)
            const float gi1 = xgB[0] + vi1, gf1 = xgB[1] + vf1;
            const float gg1 = xgB[2] + vg1, go1 = xgB[3] + vo1;
            const float iv1 = sigm(gi1), fv1 = sigm(gf1), ov1 = sigm(go1);
            const float gv1 = fmaf(2.0f, sigm(2.0f * gg1), -1.0f);
            c1 = fmaf(fv1, c1, iv1 * gv1);
            h1 = ov1 * fmaf(2.0f, sigm(2.0f * c1), -1.0f);
        }
    }

    // ---- fused fc: sum lane's 2 cols, xor-reduce over {1,2,16,32} ----
    float p = h0 * Wfc[8 * q + 2 * g] + h1 * Wfc[8 * q + 2 * g + 1];
    p += __shfl_xor(p, 1);
    p += __shfl_xor(p, 2);
    p += __shfl_xor(p, 16);
    p += __shfl_xor(p, 32);
    if (lane == 0)      out[b0]     = p + bfc[0];   // class m in {0..3}: row 0
    else if (lane == 8) out[b0 + 1] = p + bfc[0];   // class m in {8..11}: row 1
}

extern "C" void kernel_launch(void* const* d_in, const int* in_sizes, int n_in,
                              void* d_out, int out_size, void* d_ws, size_t ws_size,
                              hipStream_t stream) {
    const float* x   = (const float*)d_in[0];
    const float* Wih = (const float*)d_in[1];
    const float* Whh = (const float*)d_in[2];
    const float* bih = (const float*)d_in[3];
    const float* bhh = (const float*)d_in[4];
    const float* Wfc = (const float*)d_in[5];
    const float* bfc = (const float*)d_in[6];
    float* out = (float*)d_out;
    lstm_fused<<<dim3(256), dim3(256), 0, stream>>>(x, Wih, Whh, bih, bhh, Wfc, bfc, out);
}

// Round 4
// 433.852 us; speedup vs baseline: 1.1636x; 1.1636x over previous
//
#include <hip/hip_runtime.h>

typedef __attribute__((ext_vector_type(8))) short short8;
typedef __attribute__((ext_vector_type(4))) float f32x4;

#define LOG2E 1.44269504088896340736f
#define SC1 (-LOG2E)          // fold into i,f,o gate rows: sigma(x)=rcp(1+exp2(SC1*x))
#define SC2 (-2.0f * LOG2E)   // fold into g gate rows:    tanh(x)=2*rcp(1+exp2(SC2*x))-1

__device__ __forceinline__ unsigned pkcvt(float lo, float hi) {   // 1-instr bf16 RNE pack
    unsigned r;
    asm("v_cvt_pk_bf16_f32 %0, %1, %2" : "=v"(r) : "v"(lo), "v"(hi));
    return r;
}
__device__ __forceinline__ float sige(float xpre) {   // rcp(1+exp2(xpre)), xpre pre-scaled
    return __builtin_amdgcn_rcpf(1.0f + __builtin_amdgcn_exp2f(xpre));
}

// B=2048, T=512, I=64, H=32. R1 topology (1 row/wave, 512 blocks x 4 waves,
// 2 blocks/CU -> 2 waves/SIMD) which measured issue-saturated
// (MfmaUtil+VALUBusy ~= 98%). R4 = instruction diet + shorter h-exchange:
//  - all packs via v_cvt_pk_bf16_f32 (was ~10-instr manual pk2)
//  - -log2e / -2log2e folded into weights+bias (kills per-sigmoid mul)
//  - xg bias enters via MFMA C-operand (kills 4 adds x 8 tiles per chunk)
//  - h-exchange: DPP quad_perm (true DPP, not ds_swizzle) + cvt_pk + 4
//    independent ds_bpermute -> ONE crossbar latency, no ds_write->ds_read
//    round trip, no LDS h buffer. (R2 failed because __shfl_xor lowered to
//    ds_swizzle AND the manual pk2 was fat -- both fixed here.)
__global__ __launch_bounds__(256, 2) void lstm_fused(
    const float* __restrict__ x,    // [2048,512,64]
    const float* __restrict__ Wih,  // [128,64]
    const float* __restrict__ Whh,  // [128,32]
    const float* __restrict__ bih,  // [128]
    const float* __restrict__ bhh,  // [128]
    const float* __restrict__ Wfc,  // [1,32]
    const float* __restrict__ bfc,  // [1]
    float* __restrict__ out)        // [2048,1]
{
    __shared__ unsigned short Wlds[128 * 80];   // W_ih bf16 (pre-scaled), stride 80 (20480 B)
    __shared__ float xg_sh[4 * 16 * 132];       // per-wave 1 row xg (33792 B) -> total 54272 B

    const int tid  = threadIdx.x;
    const int lane = tid & 63;
    const int wv   = tid >> 6;
    const int b0   = blockIdx.x * 4 + wv;   // one batch row per wave
    const int m    = lane & 15;   // tile col / A-row index
    const int quad = lane >> 4;   // k-quad
    const int cc   = lane & 31;   // owned h column

    // ---- cooperative W_ih -> LDS (bf16, pre-scaled per gate type) ----
    {
        const float4* w4 = (const float4*)Wih;
        unsigned* wl = (unsigned*)Wlds;
        #pragma unroll
        for (int i = 0; i < 8; i++) {
            int fi = tid * 8 + i;            // float4 index, 2048 total
            int g  = fi >> 4;                // gate row 0..127
            int k  = (fi & 15) << 2;         // col (float units)
            const float s = ((g >> 5) == 2) ? SC2 : SC1;
            float4 v = w4[fi];
            wl[g * 40 + (k >> 1) + 0] = pkcvt(v.x * s, v.y * s);
            wl[g * 40 + (k >> 1) + 1] = pkcvt(v.z * s, v.w * s);
        }
    }

    // ---- W_hh B-frags (bf16, pre-scaled): tile t, lane holds Whh[16t+m][quad*8..+7] ----
    short8 Bh[8];
    #pragma unroll
    for (int t = 0; t < 8; t++) {
        const float s = ((t >> 1) == 2) ? SC2 : SC1;   // compile-time per tile
        const float4* wr = (const float4*)(Whh + (size_t)(16 * t + m) * 32 + quad * 8);
        float4 va = wr[0], vb = wr[1];
        union { short8 v; unsigned u[4]; } B;
        B.u[0] = pkcvt(va.x * s, va.y * s); B.u[1] = pkcvt(va.z * s, va.w * s);
        B.u[2] = pkcvt(vb.x * s, vb.y * s); B.u[3] = pkcvt(vb.z * s, vb.w * s);
        Bh[t] = B.v;
    }

    // ---- bias as MFMA C-operand splats: Cb[n] = scale*(bih+bhh)[16n+m] in all 4 rows ----
    f32x4 Cb[8];
    #pragma unroll
    for (int n = 0; n < 8; n++) {
        const float s = ((n >> 1) == 2) ? SC2 : SC1;   // compile-time per n
        const float b = s * (bih[16 * n + m] + bhh[16 * n + m]);
        Cb[n][0] = b; Cb[n][1] = b; Cb[n][2] = b; Cb[n][3] = b;
    }

    const bool b4  = (lane & 16) != 0;
    const bool odd = (lane & 1) != 0;
    const int badr = quad * 32;   // bpermute byte addr; owner of pair t is lane 8*quad+2t

    __syncthreads();  // Wlds ready; per-wave regions need no further barriers

    const float* xrow = x + ((size_t)b0 * 512 + m) * 64;    // row b0, timestep row m
    float* xgw = xg_sh + wv * 2112;                         // [16 t][132]

    float c = 0.0f, h = 0.0f;
    const f32x4 z4 = {0.f, 0.f, 0.f, 0.f};

    // prefetch chunk 0
    float4 p0, p1, p2, p3;
    {
        const float4* r0 = (const float4*)xrow;
        p0 = r0[quad * 2];     p1 = r0[quad * 2 + 1];
        p2 = r0[8 + quad * 2]; p3 = r0[8 + quad * 2 + 1];
    }

    for (int ch = 0; ch < 32; ++ch) {
        // ---- pack A-frags (k 0..31, 32..63), 1-instr packs ----
        union { short8 v; unsigned u[4]; } A0, A1;
        A0.u[0] = pkcvt(p0.x, p0.y); A0.u[1] = pkcvt(p0.z, p0.w);
        A0.u[2] = pkcvt(p1.x, p1.y); A0.u[3] = pkcvt(p1.z, p1.w);
        A1.u[0] = pkcvt(p2.x, p2.y); A1.u[1] = pkcvt(p2.z, p2.w);
        A1.u[2] = pkcvt(p3.x, p3.y); A1.u[3] = pkcvt(p3.z, p3.w);

        // ---- prefetch next chunk (hidden under the 16-step loop) ----
        {
            const int chn = (ch < 31) ? ch + 1 : 31;
            const float4* n0 = (const float4*)(xrow + (size_t)chn * 1024);
            p0 = n0[quad * 2];     p1 = n0[quad * 2 + 1];
            p2 = n0[8 + quad * 2]; p3 = n0[8 + quad * 2 + 1];
        }

        // ---- xg: 16 MFMAs, bias via C-operand; scatter [tt][4*cc+gidx] ----
        #pragma unroll
        for (int n = 0; n < 8; n++) {
            const short8 B0 = *(const short8*)&Wlds[(16 * n + m) * 80 + quad * 8];
            const short8 B1 = *(const short8*)&Wlds[(16 * n + m) * 80 + 32 + quad * 8];
            f32x4 ar0 = __builtin_amdgcn_mfma_f32_16x16x32_bf16(A0.v, B0, Cb[n], 0, 0, 0);
            ar0       = __builtin_amdgcn_mfma_f32_16x16x32_bf16(A1.v, B1, ar0,   0, 0, 0);
            const int pos = ((n & 1) << 6) + 4 * m + (n >> 1);
            #pragma unroll
            for (int r = 0; r < 4; r++) {
                xgw[(quad * 4 + r) * 132 + pos] = ar0[r];
            }
        }

        // ---- 16 recurrent timesteps ----
        #pragma unroll
        for (int tt = 0; tt < 16; ++tt) {
            // build bf16 pair (h[2i],h[2i+1]) on both lanes of each pair:
            // true DPP quad_perm xor-1 (2cy) + 2 cvt_pk + 1 cndmask
            union { float f; int i; } hu; hu.f = h;
            union { int i; float f; } hxu;
            hxu.i = __builtin_amdgcn_mov_dpp(hu.i, 0xB1, 0xF, 0xF, true); // lane^1
            const unsigned pe = pkcvt(h, hxu.f);
            const unsigned po = pkcvt(hxu.f, h);
            const int pair = odd ? (int)po : (int)pe;

            // gather A-frag h[8q..8q+7] via 4 independent bpermutes (1 crossbar hop)
            union { short8 v; int u[4]; } abf;
            abf.u[0] = __builtin_amdgcn_ds_bpermute(badr,      pair);
            abf.u[1] = __builtin_amdgcn_ds_bpermute(badr + 8,  pair);
            abf.u[2] = __builtin_amdgcn_ds_bpermute(badr + 16, pair);
            abf.u[3] = __builtin_amdgcn_ds_bpermute(badr + 24, pair);

            const f32x4 a0 = __builtin_amdgcn_mfma_f32_16x16x32_bf16(abf.v, Bh[0], z4, 0, 0, 0);
            const f32x4 a1 = __builtin_amdgcn_mfma_f32_16x16x32_bf16(abf.v, Bh[1], z4, 0, 0, 0);
            const f32x4 a2 = __builtin_amdgcn_mfma_f32_16x16x32_bf16(abf.v, Bh[2], z4, 0, 0, 0);
            const f32x4 a3 = __builtin_amdgcn_mfma_f32_16x16x32_bf16(abf.v, Bh[3], z4, 0, 0, 0);
            const f32x4 a4 = __builtin_amdgcn_mfma_f32_16x16x32_bf16(abf.v, Bh[4], z4, 0, 0, 0);
            const f32x4 a5 = __builtin_amdgcn_mfma_f32_16x16x32_bf16(abf.v, Bh[5], z4, 0, 0, 0);
            const f32x4 a6 = __builtin_amdgcn_mfma_f32_16x16x32_bf16(abf.v, Bh[6], z4, 0, 0, 0);
            const f32x4 a7 = __builtin_amdgcn_mfma_f32_16x16x32_bf16(abf.v, Bh[7], z4, 0, 0, 0);
            // lane's pre-scaled gate contributions: i=cc, f=cc+32, g=cc+64, o=cc+96
            const float hi = b4 ? a1[0] : a0[0];
            const float hf = b4 ? a3[0] : a2[0];
            const float hg = b4 ? a5[0] : a4[0];
            const float ho = b4 ? a7[0] : a6[0];

            const f32x4 xg4 = *(const f32x4*)&xgw[tt * 132 + 4 * cc];
            const float iv = sige(xg4[0] + hi);                 // sigmoid (pre-scaled)
            const float fv = sige(xg4[1] + hf);
            const float gv = fmaf(2.0f, sige(xg4[2] + hg), -1.0f);  // tanh (pre-scaled)
            const float ov = sige(xg4[3] + ho);
            c = fmaf(fv, c, iv * gv);
            const float th = fmaf(2.0f, sige(c * SC2), -1.0f);  // tanh(c)
            h = ov * th;
        }
    }

    // ---- fused fc: out[b0] = sum_cc h_cc * Wfc[cc] + bfc ----
    float p = h * Wfc[cc];
    #pragma unroll
    for (int msk = 16; msk >= 1; msk >>= 1) p += __shfl_xor(p, msk);
    if (lane == 0) out[b0] = p + bfc[0];
}

extern "C" void kernel_launch(void* const* d_in, const int* in_sizes, int n_in,
                              void* d_out, int out_size, void* d_ws, size_t ws_size,
                              hipStream_t stream) {
    const float* x   = (const float*)d_in[0];
    const float* Wih = (const float*)d_in[1];
    const float* Whh = (const float*)d_in[2];
    const float* bih = (const float*)d_in[3];
    const float* bhh = (const float*)d_in[4];
    const float* Wfc = (const float*)d_in[5];
    const float* bfc = (const float*)d_in[6];
    float* out = (float*)d_out;
    lstm_fused<<<dim3(512), dim3(256), 0, stream>>>(x, Wih, Whh, bih, bhh, Wfc, bfc, out);
}

// Round 6
// 429.476 us; speedup vs baseline: 1.1754x; 1.0102x over previous
//
#include <hip/hip_runtime.h>

typedef __attribute__((ext_vector_type(8))) short short8;
typedef __attribute__((ext_vector_type(4))) float f32x4;

#define LOG2E 1.44269504088896340736f
#define SC1 (-LOG2E)          // folded into i,f,o rows: sigma(x)=rcp(1+exp2(SC1*x))
#define SC2 (-2.0f * LOG2E)   // folded into g rows:     tanh(x)=2*rcp(1+exp2(SC2*x))-1

__device__ __forceinline__ unsigned pkcvt(float lo, float hi) {   // 1-instr bf16 RNE pack
    unsigned r;
    asm("v_cvt_pk_bf16_f32 %0, %1, %2" : "=v"(r) : "v"(lo), "v"(hi));
    return r;
}
__device__ __forceinline__ float sige(float xpre) {   // rcp(1+exp2(xpre)), xpre pre-scaled
    return __builtin_amdgcn_rcpf(1.0f + __builtin_amdgcn_exp2f(xpre));
}
__device__ __forceinline__ unsigned f2u(float f) { union { float f; unsigned u; } v; v.f = f; return v.u; }
__device__ __forceinline__ float u2f(unsigned u) { union { unsigned u; float f; } v; v.u = u; return v.f; }

// B=2048, T=512, I=64, H=32. 1 row/wave, 512 blocks x 4 waves, 2 blocks/CU.
// R6 = R5 (dual-gate lane split: lanes<32 compute (i,f) of col cc, lanes>=32
// compute (g,o); trans ops 10->6 per step) with the half-merge FIXED:
//  - use __builtin_amdgcn_permlane32_swap (two-result SSA; the R5 raw asm with
//    two "+v" operands initialized to the same value risked operand aliasing)
//  - swap DIRECTION is probed at runtime once outside the loop (feed upper?1:0;
//    whichever output is all-zero is the lower-half broadcast), then each
//    per-step merge selects with 2 cndmask -- correct under either direction.
// h-exchange stays on the proven ds_write_b16 -> ds_read_b128 path.
__global__ __launch_bounds__(256, 2) void lstm_fused(
    const float* __restrict__ x,    // [2048,512,64]
    const float* __restrict__ Wih,  // [128,64]
    const float* __restrict__ Whh,  // [128,32]
    const float* __restrict__ bih,  // [128]
    const float* __restrict__ bhh,  // [128]
    const float* __restrict__ Wfc,  // [1,32]
    const float* __restrict__ bfc,  // [1]
    float* __restrict__ out)        // [2048,1]
{
    __shared__ unsigned short Wlds[128 * 80];            // W_ih bf16 pre-scaled (20480 B)
    __shared__ float xg_sh[4 * 16 * 132];                // per-wave xg pairs   (33792 B)
    __shared__ alignas(64) unsigned short hbuf[4 * 64];  // per-wave h bf16       (512 B)

    const int tid  = threadIdx.x;
    const int lane = tid & 63;
    const int wv   = tid >> 6;
    const int b0   = blockIdx.x * 4 + wv;   // one batch row per wave
    const int m    = lane & 15;   // tile col / A-row index
    const int quad = lane >> 4;   // k-quad
    const int cc   = lane & 31;   // owned h column

    // ---- cooperative W_ih -> LDS (bf16, pre-scaled per gate type) ----
    {
        const float4* w4 = (const float4*)Wih;
        unsigned* wl = (unsigned*)Wlds;
        #pragma unroll
        for (int i = 0; i < 8; i++) {
            int fi = tid * 8 + i;            // float4 index, 2048 total
            int g  = fi >> 4;                // gate row 0..127
            int k  = (fi & 15) << 2;         // col (float units)
            const float s = ((g >> 5) == 2) ? SC2 : SC1;
            float4 v = w4[fi];
            wl[g * 40 + (k >> 1) + 0] = pkcvt(v.x * s, v.y * s);
            wl[g * 40 + (k >> 1) + 1] = pkcvt(v.z * s, v.w * s);
        }
    }

    // ---- W_hh B-frags (bf16, pre-scaled): tile t, lane holds Whh[16t+m][quad*8..+7] ----
    short8 Bh[8];
    #pragma unroll
    for (int t = 0; t < 8; t++) {
        const float s = ((t >> 1) == 2) ? SC2 : SC1;   // compile-time per tile
        const float4* wr = (const float4*)(Whh + (size_t)(16 * t + m) * 32 + quad * 8);
        float4 va = wr[0], vb = wr[1];
        union { short8 v; unsigned u[4]; } B;
        B.u[0] = pkcvt(va.x * s, va.y * s); B.u[1] = pkcvt(va.z * s, va.w * s);
        B.u[2] = pkcvt(vb.x * s, vb.y * s); B.u[3] = pkcvt(vb.z * s, vb.w * s);
        Bh[t] = B.v;
    }

    // ---- bias as MFMA C-operand splats: Cb[n] = scale*(bih+bhh)[16n+m] ----
    f32x4 Cb[8];
    #pragma unroll
    for (int n = 0; n < 8; n++) {
        const float s = ((n >> 1) == 2) ? SC2 : SC1;   // compile-time per n
        const float b = s * (bih[16 * n + m] + bhh[16 * n + m]);
        Cb[n][0] = b; Cb[n][1] = b; Cb[n][2] = b; Cb[n][3] = b;
    }

    const bool b4    = (lane & 16) != 0;
    const bool upper = (lane & 32) != 0;

    // ---- probe permlane32_swap direction (once; wave-uniform result) ----
    // Whichever output returns the lower-half broadcast is our "lo" slot.
    bool x_lo;
    {
        const unsigned probe = upper ? 1u : 0u;
        auto dr = __builtin_amdgcn_permlane32_swap(probe, probe, false, false);
        x_lo = (dr[0] == 0u);
    }

    __syncthreads();  // Wlds ready; per-wave regions need no further barriers

    const float* xrow = x + ((size_t)b0 * 512 + m) * 64;    // row b0, timestep row m
    float* xgw = xg_sh + wv * 2112;                         // [16 tt][132]
    unsigned short* hw = hbuf + wv * 64;

    hw[lane] = 0;
    float c = 0.0f, h = 0.0f;
    const f32x4 z4 = {0.f, 0.f, 0.f, 0.f};

    // prefetch chunk 0
    float4 p0, p1, p2, p3;
    {
        const float4* r0 = (const float4*)xrow;
        p0 = r0[quad * 2];     p1 = r0[quad * 2 + 1];
        p2 = r0[8 + quad * 2]; p3 = r0[8 + quad * 2 + 1];
    }

    for (int ch = 0; ch < 32; ++ch) {
        // ---- pack A-frags (k 0..31, 32..63) ----
        union { short8 v; unsigned u[4]; } A0, A1;
        A0.u[0] = pkcvt(p0.x, p0.y); A0.u[1] = pkcvt(p0.z, p0.w);
        A0.u[2] = pkcvt(p1.x, p1.y); A0.u[3] = pkcvt(p1.z, p1.w);
        A1.u[0] = pkcvt(p2.x, p2.y); A1.u[1] = pkcvt(p2.z, p2.w);
        A1.u[2] = pkcvt(p3.x, p3.y); A1.u[3] = pkcvt(p3.z, p3.w);

        // ---- prefetch next chunk (hidden under the 16-step loop) ----
        {
            const int chn = (ch < 31) ? ch + 1 : 31;
            const float4* n0 = (const float4*)(xrow + (size_t)chn * 1024);
            p0 = n0[quad * 2];     p1 = n0[quad * 2 + 1];
            p2 = n0[8 + quad * 2]; p3 = n0[8 + quad * 2 + 1];
        }

        // ---- xg: 16 MFMAs, bias via C-operand; dual-pair scatter ----
        // gate 16n+m at tt=4q+r -> float idx 2m + 32(n&1) + 64(n>>2) + ((n>>1)&1):
        // reader lane L gets (i|g, f|o) of its column at [tt*132 + 2L].
        #pragma unroll
        for (int n = 0; n < 8; n++) {
            const short8 B0 = *(const short8*)&Wlds[(16 * n + m) * 80 + quad * 8];
            const short8 B1 = *(const short8*)&Wlds[(16 * n + m) * 80 + 32 + quad * 8];
            f32x4 ar0 = __builtin_amdgcn_mfma_f32_16x16x32_bf16(A0.v, B0, Cb[n], 0, 0, 0);
            ar0       = __builtin_amdgcn_mfma_f32_16x16x32_bf16(A1.v, B1, ar0,   0, 0, 0);
            const int so = 2 * m + 32 * (n & 1) + 64 * (n >> 2) + ((n >> 1) & 1);
            #pragma unroll
            for (int r = 0; r < 4; r++) {
                xgw[(quad * 4 + r) * 132 + so] = ar0[r];
            }
        }

        // ---- 16 recurrent timesteps ----
        #pragma unroll
        for (int tt = 0; tt < 16; ++tt) {
            const short8 abf = *(const short8*)&hw[quad * 8];
            const f32x4 a0 = __builtin_amdgcn_mfma_f32_16x16x32_bf16(abf, Bh[0], z4, 0, 0, 0);
            const f32x4 a1 = __builtin_amdgcn_mfma_f32_16x16x32_bf16(abf, Bh[1], z4, 0, 0, 0);
            const f32x4 a4 = __builtin_amdgcn_mfma_f32_16x16x32_bf16(abf, Bh[4], z4, 0, 0, 0);
            const f32x4 a5 = __builtin_amdgcn_mfma_f32_16x16x32_bf16(abf, Bh[5], z4, 0, 0, 0);
            const f32x4 a2 = __builtin_amdgcn_mfma_f32_16x16x32_bf16(abf, Bh[2], z4, 0, 0, 0);
            const f32x4 a3 = __builtin_amdgcn_mfma_f32_16x16x32_bf16(abf, Bh[3], z4, 0, 0, 0);
            const f32x4 a6 = __builtin_amdgcn_mfma_f32_16x16x32_bf16(abf, Bh[6], z4, 0, 0, 0);
            const f32x4 a7 = __builtin_amdgcn_mfma_f32_16x16x32_bf16(abf, Bh[7], z4, 0, 0, 0);

            // lane<32: hA = i-contrib(cc), hB = f-contrib; lane>=32: g, o
            const float gaL = b4 ? a1[0] : a0[0];
            const float gaU = b4 ? a5[0] : a4[0];
            const float gbL = b4 ? a3[0] : a2[0];
            const float gbU = b4 ? a7[0] : a6[0];
            const float hA  = upper ? gaU : gaL;
            const float hB  = upper ? gbU : gbL;

            const float2 xg2 = *(const float2*)&xgw[tt * 132 + 2 * lane];
            const float s1 = sige(xg2.x + hA);   // lane<32: sigma(i) | lane>=32: sig-form(g)
            const float s2 = sige(xg2.y + hB);   // lane<32: sigma(f) | lane>=32: sig-form(o)

            // merge halves: one swap -> {lo-bcast, hi-bcast}; pick via probed x_lo
            auto r1 = __builtin_amdgcn_permlane32_swap(f2u(s1), f2u(s1), false, false);
            const float iv  = u2f(x_lo ? r1[0] : r1[1]);
            const float gvr = u2f(x_lo ? r1[1] : r1[0]);
            auto r2 = __builtin_amdgcn_permlane32_swap(f2u(s2), f2u(s2), false, false);
            const float fv = u2f(x_lo ? r2[0] : r2[1]);
            const float ov = u2f(x_lo ? r2[1] : r2[0]);

            const float gv = fmaf(2.0f, gvr, -1.0f);        // tanh(g)
            c = fmaf(fv, c, iv * gv);
            const float th = sige(c * SC2);                 // sig-form of tanh(c)
            h = fmaf(ov + ov, th, -ov);                     // ov*(2*th-1)
            hw[lane] = (unsigned short)pkcvt(h, h);         // bf16 store (RNE)
        }
    }

    // ---- fused fc: out[b0] = sum_cc h_cc * Wfc[cc] + bfc ----
    float p = h * Wfc[cc];
    #pragma unroll
    for (int msk = 16; msk >= 1; msk >>= 1) p += __shfl_xor(p, msk);
    if (lane == 0) out[b0] = p + bfc[0];
}

extern "C" void kernel_launch(void* const* d_in, const int* in_sizes, int n_in,
                              void* d_out, int out_size, void* d_ws, size_t ws_size,
                              hipStream_t stream) {
    const float* x   = (const float*)d_in[0];
    const float* Wih = (const float*)d_in[1];
    const float* Whh = (const float*)d_in[2];
    const float* bih = (const float*)d_in[3];
    const float* bhh = (const float*)d_in[4];
    const float* Wfc = (const float*)d_in[5];
    const float* bfc = (const float*)d_in[6];
    float* out = (float*)d_out;
    lstm_fused<<<dim3(512), dim3(256), 0, stream>>>(x, Wih, Whh, bih, bhh, Wfc, bfc, out);
}